// Round 5
// baseline (235.844 us; speedup 1.0000x reference)
//
#include <hip/hip_runtime.h>
#include <hip/hip_bf16.h>

// WindowAttention v5: FUSED qkv+attention per window (no q/k/v HBM round-trip).
// N=128 tokens, B_=1024 windows, C=192, H=6, hd=32.
// Per block (window): x -> A-frag registers; per head: W B-frags from L2,
// q/k/v through small LDS tiles, QK^T + skip-max exp2 softmax (log2 domain),
// swapped PV (O^T = mfma(V^T, P)), bf16 aout -> ws; then proj GEMM.
// ws: biasF f32[6][16384] (frag order, xLOG2E) | maskF f32[64][16384] (xLOG2E) |
//     wbf bf16[576][192] | pwbf bf16[192][192] | aoutb bf16 [b][128][192]

typedef float f32x4 __attribute__((ext_vector_type(4)));
typedef short short8 __attribute__((ext_vector_type(8)));
typedef short short4e __attribute__((ext_vector_type(4)));

#define SCALE 0.17677669529663687f
#define LOG2E 1.4426950408889634f
#define QSC (SCALE * LOG2E)

static __device__ __forceinline__ short f2bf(float f) {
  __hip_bfloat16 h = __float2bfloat16(f);
  return __builtin_bit_cast(short, h);
}
static __device__ __forceinline__ f32x4 mfma16(short8 a, short8 b, f32x4 c) {
  return __builtin_amdgcn_mfma_f32_16x16x32_bf16(a, b, c, 0, 0, 0);
}

// ---------------- prep: convert qkv_w/proj_w to bf16 ----------------
__global__ __launch_bounds__(256) void prep_w(const float* __restrict__ qkvw,
                                              const float* __restrict__ projw,
                                              short* __restrict__ wbf,
                                              short* __restrict__ pwbf) {
  int t = blockIdx.x * 256 + threadIdx.x;  // float4 index 0..36863
  const int NQ = 27648;                    // 576*192/4
  float4 f; short* dst;
  if (t < NQ) { f = ((const float4*)qkvw)[t]; dst = wbf + t * 4; }
  else        { f = ((const float4*)projw)[t - NQ]; dst = pwbf + (t - NQ) * 4; }
  short4e o; o[0] = f2bf(f.x); o[1] = f2bf(f.y); o[2] = f2bf(f.z); o[3] = f2bf(f.w);
  *(short4e*)dst = o;
}

// ---------------- prep bias tiles (fragment layout, x LOG2E) ----------------
__global__ __launch_bounds__(256) void prep_bias(const int* __restrict__ rel,
                                                 const float* __restrict__ table,
                                                 float* __restrict__ biasF) {
  int blk = blockIdx.x;            // 96 blocks: h*16 + L
  int h = blk >> 4, L = blk & 15;
  int tid = threadIdx.x, lane = tid & 63, wave = tid >> 6;
  int lr = lane & 15, r4 = (lane >> 4) * 4;
  int rf = L >> 3, rg = (L >> 1) & 3, cp = L & 1;
  int row = wave * 32 + rf * 16 + r4 + rg;
  float4 v;
#pragma unroll
  for (int e = 0; e < 4; ++e) {
    int col = (cp * 4 + e) * 16 + lr;
    ((float*)&v)[e] = table[rel[row * 128 + col] * 6 + h] * LOG2E;
  }
  ((float4*)(biasF + (size_t)h * 16384))[L * 256 + tid] = v;
}

// ---------------- prep mask tiles (fragment layout, x LOG2E) ----------------
__global__ __launch_bounds__(256) void prep_mask(const float* __restrict__ mask,
                                                 float* __restrict__ maskF) {
  int blk = blockIdx.x;            // 1024 blocks: w*16 + L
  int w = blk >> 4, L = blk & 15;
  int tid = threadIdx.x, lane = tid & 63, wave = tid >> 6;
  int lr = lane & 15, r4 = (lane >> 4) * 4;
  int rf = L >> 3, rg = (L >> 1) & 3, cp = L & 1;
  int row = wave * 32 + rf * 16 + r4 + rg;
  const float* src = mask + (size_t)w * 16384 + row * 128;
  float4 v;
#pragma unroll
  for (int e = 0; e < 4; ++e) {
    int col = (cp * 4 + e) * 16 + lr;
    ((float*)&v)[e] = src[col] * LOG2E;
  }
  ((float4*)(maskF + (size_t)w * 16384))[L * 256 + tid] = v;
}

// ---------------- fused qkv + attention per window ----------------
__global__ __launch_bounds__(256, 2) void fused_kernel(const float* __restrict__ x,
                                                       const short* __restrict__ wbf,
                                                       const float* __restrict__ biasF,
                                                       const float* __restrict__ maskF,
                                                       short* __restrict__ aoutb) {
  __shared__ short q_lds[128 * 40];   // [token][40] padded, 10240 B
  __shared__ short k_lds[128 * 40];   // [token][40] padded, 10240 B
  __shared__ short v_lds[32 * 136];   // V^T [d][136] padded, 8704 B
  __shared__ short p_lds[128 * 128];  // swizzle byte ^= (row&15)<<4, 32768 B
  char* pbuf = (char*)p_lds;
  const char* vbuf = (const char*)v_lds;
  const int b = blockIdx.x;
  const int tid = threadIdx.x, wave = tid >> 6, lane = tid & 63;
  const int lr = lane & 15, g = lane >> 4, r4 = g * 4;
  const int rowbase = wave * 32;
  const float4* mF4 = (const float4*)(maskF + (size_t)(b & 63) * 16384);

  // ---- load x A-fragments: wave's 32 token rows, f32 -> bf16 ----
  short8 xa[2][6];
  {
    const float* xr = x + (size_t)b * 24576 + (size_t)(rowbase + lr) * 192;
#pragma unroll
    for (int rf = 0; rf < 2; ++rf)
#pragma unroll
      for (int ks = 0; ks < 6; ++ks) {
        const float* p = xr + rf * 16 * 192 + ks * 32 + g * 8;
        float4 f0 = *(const float4*)p;
        float4 f1 = *(const float4*)(p + 4);
        short8 v8;
        v8[0] = f2bf(f0.x); v8[1] = f2bf(f0.y); v8[2] = f2bf(f0.z); v8[3] = f2bf(f0.w);
        v8[4] = f2bf(f1.x); v8[5] = f2bf(f1.y); v8[6] = f2bf(f1.z); v8[7] = f2bf(f1.w);
        xa[rf][ks] = v8;
      }
  }

  for (int h = 0; h < 6; ++h) {
    // ---- q = x @ Wq^T (rows h*32..), scaled, -> q_lds [token][40] ----
    {
      f32x4 a[2][2];
      a[0][0] = a[0][1] = a[1][0] = a[1][1] = f32x4{0.f, 0.f, 0.f, 0.f};
#pragma unroll
      for (int cf = 0; cf < 2; ++cf) {
        const short* wr = wbf + (size_t)(h * 32 + cf * 16 + lr) * 192 + g * 8;
#pragma unroll
        for (int ks = 0; ks < 6; ++ks) {
          short8 wf = *(const short8*)(wr + ks * 32);
          a[0][cf] = mfma16(xa[0][ks], wf, a[0][cf]);
          a[1][cf] = mfma16(xa[1][ks], wf, a[1][cf]);
        }
      }
#pragma unroll
      for (int rf = 0; rf < 2; ++rf)
#pragma unroll
        for (int cf = 0; cf < 2; ++cf)
#pragma unroll
          for (int rg = 0; rg < 4; ++rg)
            q_lds[(rowbase + rf * 16 + r4 + rg) * 40 + cf * 16 + lr] =
                f2bf(a[rf][cf][rg] * QSC);
    }
    // ---- k = x @ Wk^T -> k_lds [token][40] ----
    {
      f32x4 a[2][2];
      a[0][0] = a[0][1] = a[1][0] = a[1][1] = f32x4{0.f, 0.f, 0.f, 0.f};
#pragma unroll
      for (int cf = 0; cf < 2; ++cf) {
        const short* wr = wbf + (size_t)(192 + h * 32 + cf * 16 + lr) * 192 + g * 8;
#pragma unroll
        for (int ks = 0; ks < 6; ++ks) {
          short8 wf = *(const short8*)(wr + ks * 32);
          a[0][cf] = mfma16(xa[0][ks], wf, a[0][cf]);
          a[1][cf] = mfma16(xa[1][ks], wf, a[1][cf]);
        }
      }
#pragma unroll
      for (int rf = 0; rf < 2; ++rf)
#pragma unroll
        for (int cf = 0; cf < 2; ++cf)
#pragma unroll
          for (int rg = 0; rg < 4; ++rg)
            k_lds[(rowbase + rf * 16 + r4 + rg) * 40 + cf * 16 + lr] =
                f2bf(a[rf][cf][rg]);
    }
    // ---- v^T: swapped mfma(Wv, x) -> D[d][token] -> v_lds [d][136] ----
    {
      f32x4 a[2][2];
      a[0][0] = a[0][1] = a[1][0] = a[1][1] = f32x4{0.f, 0.f, 0.f, 0.f};
#pragma unroll
      for (int df = 0; df < 2; ++df) {
        const short* wr = wbf + (size_t)(384 + h * 32 + df * 16 + lr) * 192 + g * 8;
#pragma unroll
        for (int ks = 0; ks < 6; ++ks) {
          short8 wf = *(const short8*)(wr + ks * 32);
          a[df][0] = mfma16(wf, xa[0][ks], a[df][0]);
          a[df][1] = mfma16(wf, xa[1][ks], a[df][1]);
        }
      }
#pragma unroll
      for (int df = 0; df < 2; ++df)
#pragma unroll
        for (int tf = 0; tf < 2; ++tf)
#pragma unroll
          for (int rg = 0; rg < 4; ++rg)
            v_lds[(df * 16 + r4 + rg) * 136 + rowbase + tf * 16 + lr] =
                f2bf(a[df][tf][rg]);
    }
    __syncthreads();  // k,v (cross-wave) visible

    // ---- QK^T + softmax (skip-max, log2 domain), P*inv -> p_lds ----
    const float4* bF4 = (const float4*)(biasF + (size_t)h * 16384);
#pragma unroll
    for (int rf = 0; rf < 2; ++rf) {
      short8 qa = *(const short8*)(q_lds + (rowbase + rf * 16 + lr) * 40 + g * 8);
      f32x4 s[8];
      __builtin_amdgcn_s_setprio(1);
#pragma unroll
      for (int cf = 0; cf < 8; ++cf) {
        short8 kb = *(const short8*)(k_lds + (cf * 16 + lr) * 40 + g * 8);
        f32x4 z = {0.f, 0.f, 0.f, 0.f};
        s[cf] = mfma16(qa, kb, z);
      }
      __builtin_amdgcn_s_setprio(0);
#pragma unroll
      for (int rg = 0; rg < 4; ++rg) {
        int L = rf * 8 + rg * 2;
        float4 bb0 = bF4[L * 256 + tid];
        float4 bb1 = bF4[(L + 1) * 256 + tid];
        float4 mm0 = mF4[L * 256 + tid];
        float4 mm1 = mF4[(L + 1) * 256 + tid];
        float p0 = exp2f(s[0][rg] + bb0.x + mm0.x);
        float p1 = exp2f(s[1][rg] + bb0.y + mm0.y);
        float p2 = exp2f(s[2][rg] + bb0.z + mm0.z);
        float p3 = exp2f(s[3][rg] + bb0.w + mm0.w);
        float p4 = exp2f(s[4][rg] + bb1.x + mm1.x);
        float p5 = exp2f(s[5][rg] + bb1.y + mm1.y);
        float p6 = exp2f(s[6][rg] + bb1.z + mm1.z);
        float p7 = exp2f(s[7][rg] + bb1.w + mm1.w);
        float sum = ((p0 + p1) + (p2 + p3)) + ((p4 + p5) + (p6 + p7));
#pragma unroll
        for (int o = 1; o < 16; o <<= 1) sum += __shfl_xor(sum, o);
        float inv = 1.0f / sum;
        int row = rowbase + rf * 16 + r4 + rg;
        int base = (row << 8) + (lr << 1);
        int swz = (row & 15) << 4;
        *(short*)(pbuf + ((base + 0 * 32) ^ swz)) = f2bf(p0 * inv);
        *(short*)(pbuf + ((base + 1 * 32) ^ swz)) = f2bf(p1 * inv);
        *(short*)(pbuf + ((base + 2 * 32) ^ swz)) = f2bf(p2 * inv);
        *(short*)(pbuf + ((base + 3 * 32) ^ swz)) = f2bf(p3 * inv);
        *(short*)(pbuf + ((base + 4 * 32) ^ swz)) = f2bf(p4 * inv);
        *(short*)(pbuf + ((base + 5 * 32) ^ swz)) = f2bf(p5 * inv);
        *(short*)(pbuf + ((base + 6 * 32) ^ swz)) = f2bf(p6 * inv);
        *(short*)(pbuf + ((base + 7 * 32) ^ swz)) = f2bf(p7 * inv);
      }
    }
    // ---- swapped PV: O^T = mfma(V^T, P) ; D col=token, row=d ----
    f32x4 o_[2][2];
    o_[0][0] = o_[0][1] = o_[1][0] = o_[1][1] = f32x4{0.f, 0.f, 0.f, 0.f};
    const int rsw = lr << 4;
#pragma unroll
    for (int ks = 0; ks < 4; ++ks) {
      short8 va0 = *(const short8*)(vbuf + lr * 272 + ks * 64 + g * 16);
      short8 va1 = *(const short8*)(vbuf + (16 + lr) * 272 + ks * 64 + g * 16);
      short8 pb0 = *(const short8*)(pbuf + ((((rowbase + lr) << 8) + (ks << 6) + (g << 4)) ^ rsw));
      short8 pb1 = *(const short8*)(pbuf + ((((rowbase + 16 + lr) << 8) + (ks << 6) + (g << 4)) ^ rsw));
      __builtin_amdgcn_s_setprio(1);
      o_[0][0] = mfma16(va0, pb0, o_[0][0]);
      o_[0][1] = mfma16(va0, pb1, o_[0][1]);
      o_[1][0] = mfma16(va1, pb0, o_[1][0]);
      o_[1][1] = mfma16(va1, pb1, o_[1][1]);
      __builtin_amdgcn_s_setprio(0);
    }
    // ---- store O^T frags as contiguous short4: aout[b][token][h*32+d] ----
#pragma unroll
    for (int df = 0; df < 2; ++df)
#pragma unroll
      for (int tf = 0; tf < 2; ++tf) {
        short4e s4;
        s4[0] = f2bf(o_[df][tf][0]);
        s4[1] = f2bf(o_[df][tf][1]);
        s4[2] = f2bf(o_[df][tf][2]);
        s4[3] = f2bf(o_[df][tf][3]);
        *(short4e*)(aoutb + ((size_t)b * 128 + rowbase + tf * 16 + lr) * 192 +
                    h * 32 + df * 16 + r4) = s4;
      }
    __syncthreads();  // all LDS reads done before next head overwrites
  }
}

// ---------------- proj: ain[128][192] @ proj_w^T + b ----------------
__global__ __launch_bounds__(256, 2) void proj_kernel(const short* __restrict__ ainb,
                                                      const short* __restrict__ pwbf,
                                                      const float* __restrict__ pb,
                                                      float* __restrict__ out) {
  __shared__ short at[24576];
  __shared__ short wt[2][6144];
  const int b = blockIdx.x, tid = threadIdx.x;
  const int wave = tid >> 6, lane = tid & 63;
  const int lr = lane & 15, g = lane >> 4;
  const int g16 = g * 16, r4 = g * 4;
  const int rowbase = wave * 32;
  const int xorkey = (lr & 7) << 4;
  char* atb = (char*)at;
  char* wtb = (char*)wt;

  int wsoff[3], wdoff[3];
#pragma unroll
  for (int i = 0; i < 3; ++i) {
    int idx8 = i * 256 + tid;
    int r = idx8 / 24, c = idx8 - r * 24;
    wsoff[i] = idx8 * 8;
    wdoff[i] = r * 384 + ((c * 16) ^ ((r & 7) << 4));
  }
  short8 wreg[3];
#pragma unroll
  for (int i = 0; i < 3; ++i) wreg[i] = *(const short8*)(pwbf + wsoff[i]);

  const short8* ar = (const short8*)(ainb + (size_t)b * 24576);
#pragma unroll
  for (int i = 0; i < 12; ++i) {
    int idx8 = i * 256 + tid;
    int r = idx8 / 24, c = idx8 - r * 24;
    short8 v = ar[idx8];
    *(short8*)(atb + r * 384 + ((c * 16) ^ ((r & 7) << 4))) = v;
  }
#pragma unroll
  for (int i = 0; i < 3; ++i) *(short8*)(wtb + wdoff[i]) = wreg[i];
  __syncthreads();

  const int rA0 = (rowbase + lr) * 384, rA1 = rA0 + 16 * 384;
  const int wB0 = lr * 384, wB1 = wB0 + 16 * 384;

  for (int ch = 0; ch < 6; ++ch) {
    if (ch < 5) {
#pragma unroll
      for (int i = 0; i < 3; ++i)
        wreg[i] = *(const short8*)(pwbf + (ch + 1) * 6144 + wsoff[i]);
    }
    const char* wbuf = wtb + (ch & 1) * 12288;
    f32x4 acc[2][2];
    acc[0][0] = acc[0][1] = acc[1][0] = acc[1][1] = f32x4{0.f, 0.f, 0.f, 0.f};
#pragma unroll
    for (int ks = 0; ks < 6; ++ks) {
      int cx = (ks * 64 + g16) ^ xorkey;
      short8 xa0 = *(const short8*)(atb + rA0 + cx);
      short8 xa1 = *(const short8*)(atb + rA1 + cx);
      short8 wf0 = *(const short8*)(wbuf + wB0 + cx);
      short8 wf1 = *(const short8*)(wbuf + wB1 + cx);
      acc[0][0] = mfma16(xa0, wf0, acc[0][0]);
      acc[0][1] = mfma16(xa0, wf1, acc[0][1]);
      acc[1][0] = mfma16(xa1, wf0, acc[1][0]);
      acc[1][1] = mfma16(xa1, wf1, acc[1][1]);
    }
#pragma unroll
    for (int cf = 0; cf < 2; ++cf) {
      int j = ch * 32 + cf * 16 + lr;
      float bj = pb[j];
#pragma unroll
      for (int rf = 0; rf < 2; ++rf)
#pragma unroll
        for (int rg = 0; rg < 4; ++rg) {
          int tok = rowbase + rf * 16 + r4 + rg;
          out[((size_t)b * 128 + tok) * 192 + j] = acc[rf][cf][rg] + bj;
        }
    }
    if (ch < 5) {
#pragma unroll
      for (int i = 0; i < 3; ++i)
        *(short8*)(wtb + ((ch + 1) & 1) * 12288 + wdoff[i]) = wreg[i];
      __syncthreads();
    }
  }
}

extern "C" void kernel_launch(void* const* d_in, const int* in_sizes, int n_in,
                              void* d_out, int out_size, void* d_ws, size_t ws_size,
                              hipStream_t stream) {
  const float* x      = (const float*)d_in[0];
  const float* mask   = (const float*)d_in[1];
  const float* qkv_w  = (const float*)d_in[2];
  const float* proj_w = (const float*)d_in[3];
  const float* proj_b = (const float*)d_in[4];
  const float* table  = (const float*)d_in[5];
  const int*   rel    = (const int*)d_in[6];
  char* ws = (char*)d_ws;
  size_t o = 0;
  float* biasF = (float*)(ws + o); o += 393216;
  float* maskF = (float*)(ws + o); o += 4194304;
  short* wbf   = (short*)(ws + o); o += 221184;
  short* pwbf  = (short*)(ws + o); o += 73728;
  short* aoutb = (short*)(ws + o);
  float* out = (float*)d_out;

  prep_w<<<144, 256, 0, stream>>>(qkv_w, proj_w, wbf, pwbf);
  prep_bias<<<96, 256, 0, stream>>>(rel, table, biasF);
  prep_mask<<<1024, 256, 0, stream>>>(mask, maskF);
  fused_kernel<<<1024, 256, 0, stream>>>(x, wbf, biasF, maskF, aoutb);
  proj_kernel<<<1024, 256, 0, stream>>>(aoutb, pwbf, proj_b, out);
}

// Round 6
// 201.691 us; speedup vs baseline: 1.1693x; 1.1693x over previous
//
#include <hip/hip_runtime.h>
#include <hip/hip_bf16.h>

// WindowAttention v6: v4 pipeline + pre-summed bias+mask (bmF) + 5-block/CU attn.
// N=128 tokens, B_=1024 windows, C=192, H=6, hd=32.
// ws: bmF f32 [6*64][16384] (fragment order, (bias+mask)*LOG2E) |
//     wbf bf16[576][192] | pwbf bf16[192][192] |
//     q bf16 [b][h][n][d] (pre-scaled SCALE*LOG2E) | k bf16 | v bf16 [b][h][d][n]
// attn output (bf16) lives in d_out: slot b = d_out + b*98304 + 49152 (block-private).
// Fragment order: tile[L*1024 + tid*4 + e], L = rf*8+rg*2+cp, col=(cp*4+e)*16+lr,
//   row = wave*32+rf*16+r4+rg.

typedef float f32x4 __attribute__((ext_vector_type(4)));
typedef short short8 __attribute__((ext_vector_type(8)));
typedef short short4e __attribute__((ext_vector_type(4)));

#define SCALE 0.17677669529663687f
#define LOG2E 1.4426950408889634f
#define QSC (SCALE * LOG2E)

static __device__ __forceinline__ short f2bf(float f) {
  __hip_bfloat16 h = __float2bfloat16(f);
  return __builtin_bit_cast(short, h);
}
static __device__ __forceinline__ f32x4 mfma16(short8 a, short8 b, f32x4 c) {
  return __builtin_amdgcn_mfma_f32_16x16x32_bf16(a, b, c, 0, 0, 0);
}

// ---------------- prep: convert qkv_w/proj_w to bf16 ----------------
__global__ __launch_bounds__(256) void prep_w(const float* __restrict__ qkvw,
                                              const float* __restrict__ projw,
                                              short* __restrict__ wbf,
                                              short* __restrict__ pwbf) {
  int t = blockIdx.x * 256 + threadIdx.x;  // float4 index 0..36863
  const int NQ = 27648;                    // 576*192/4
  float4 f; short* dst;
  if (t < NQ) { f = ((const float4*)qkvw)[t]; dst = wbf + t * 4; }
  else        { f = ((const float4*)projw)[t - NQ]; dst = pwbf + (t - NQ) * 4; }
  short4e o; o[0] = f2bf(f.x); o[1] = f2bf(f.y); o[2] = f2bf(f.z); o[3] = f2bf(f.w);
  *(short4e*)dst = o;
}

// ---------------- prep_bm: (bias+mask)*LOG2E tiles, fragment layout ----------------
__global__ __launch_bounds__(256) void prep_bm(const int* __restrict__ rel,
                                               const float* __restrict__ table,
                                               const float* __restrict__ mask,
                                               float* __restrict__ bmF) {
  int blk = blockIdx.x;            // 384 blocks: h*64 + w
  int h = blk >> 6, w = blk & 63;
  int tid = threadIdx.x, lane = tid & 63, wave = tid >> 6;
  int lr = lane & 15, r4 = (lane >> 4) * 4;
  const float* mk = mask + (size_t)w * 16384;
  float* dst = bmF + (size_t)blk * 16384;
#pragma unroll
  for (int L = 0; L < 16; ++L) {
    int rf = L >> 3, rg = (L >> 1) & 3, cp = L & 1;
    int row = wave * 32 + rf * 16 + r4 + rg;
    float4 v;
#pragma unroll
    for (int e = 0; e < 4; ++e) {
      int col = (cp * 4 + e) * 16 + lr;
      float bias = table[rel[row * 128 + col] * 6 + h];
      ((float*)&v)[e] = (bias + mk[row * 128 + col]) * LOG2E;
    }
    ((float4*)dst)[L * 256 + tid] = v;
  }
}

// ---------------- qkv: x[128][192] @ W^T, W streamed in 32-col bf16 chunks ----------------
__global__ __launch_bounds__(256, 2) void qkv_kernel(const float* __restrict__ x,
                                                     const short* __restrict__ wbf,
                                                     short* __restrict__ qb,
                                                     short* __restrict__ kb,
                                                     short* __restrict__ vb) {
  __shared__ short xt[24576];    // [128][192] bf16, XOR-swizzled (byte ^= (row&7)<<4)
  __shared__ short wt[2][6144];  // [32][192] bf16 double buffer, same swizzle
  const int b = blockIdx.x, tid = threadIdx.x;
  const int wave = tid >> 6, lane = tid & 63;
  const int lr = lane & 15, g = lane >> 4;
  const int g16 = g * 16, r4 = g * 4;
  const int rowbase = wave * 32;
  const int xorkey = (lr & 7) << 4;
  char* xtb = (char*)xt;
  char* wtb = (char*)wt;

  int wsoff[3], wdoff[3];
#pragma unroll
  for (int i = 0; i < 3; ++i) {
    int idx8 = i * 256 + tid;
    int r = idx8 / 24, c = idx8 - r * 24;
    wsoff[i] = idx8 * 8;
    wdoff[i] = r * 384 + ((c * 16) ^ ((r & 7) << 4));
  }
  short8 wreg[3];
#pragma unroll
  for (int i = 0; i < 3; ++i) wreg[i] = *(const short8*)(wbf + wsoff[i]);

  const float4* xr = (const float4*)(x + (size_t)b * 24576);
  for (int s = tid; s < 6144; s += 256) {
    float4 f = xr[s];
    int r = s / 48, c8 = s - r * 48;
    int off = r * 384 + ((c8 * 8) ^ ((r & 7) << 4));
    short4e o; o[0] = f2bf(f.x); o[1] = f2bf(f.y); o[2] = f2bf(f.z); o[3] = f2bf(f.w);
    *(short4e*)(xtb + off) = o;
  }
#pragma unroll
  for (int i = 0; i < 3; ++i) *(short8*)(wtb + wdoff[i]) = wreg[i];
  __syncthreads();

  const int rA0 = (rowbase + lr) * 384, rA1 = rA0 + 16 * 384;
  const int wB0 = lr * 384, wB1 = wB0 + 16 * 384;

  for (int ch = 0; ch < 18; ++ch) {
    if (ch < 17) {
#pragma unroll
      for (int i = 0; i < 3; ++i)
        wreg[i] = *(const short8*)(wbf + (ch + 1) * 6144 + wsoff[i]);
    }
    const char* wbuf = wtb + (ch & 1) * 12288;
    f32x4 acc[2][2];
    acc[0][0] = acc[0][1] = acc[1][0] = acc[1][1] = f32x4{0.f, 0.f, 0.f, 0.f};
    const bool isv = (ch >= 12);
#pragma unroll
    for (int ks = 0; ks < 6; ++ks) {
      int cx = (ks * 64 + g16) ^ xorkey;
      short8 xa0 = *(const short8*)(xtb + rA0 + cx);
      short8 xa1 = *(const short8*)(xtb + rA1 + cx);
      short8 wf0 = *(const short8*)(wbuf + wB0 + cx);
      short8 wf1 = *(const short8*)(wbuf + wB1 + cx);
      if (!isv) {
        acc[0][0] = mfma16(xa0, wf0, acc[0][0]);
        acc[0][1] = mfma16(xa0, wf1, acc[0][1]);
        acc[1][0] = mfma16(xa1, wf0, acc[1][0]);
        acc[1][1] = mfma16(xa1, wf1, acc[1][1]);
      } else {
        acc[0][0] = mfma16(wf0, xa0, acc[0][0]);
        acc[0][1] = mfma16(wf0, xa1, acc[0][1]);
        acc[1][0] = mfma16(wf1, xa0, acc[1][0]);
        acc[1][1] = mfma16(wf1, xa1, acc[1][1]);
      }
    }
    if (!isv) {
      int h = (ch < 6) ? ch : ch - 6;
      short* dst = (ch < 6) ? qb : kb;
      float sc = (ch < 6) ? QSC : 1.0f;
      size_t base = ((size_t)b * 6 + h) * 4096;
#pragma unroll
      for (int rf = 0; rf < 2; ++rf)
#pragma unroll
        for (int cf = 0; cf < 2; ++cf) {
          int d = cf * 16 + lr;
#pragma unroll
          for (int rg = 0; rg < 4; ++rg) {
            int tok = rowbase + rf * 16 + r4 + rg;
            dst[base + (size_t)tok * 32 + d] = f2bf(acc[rf][cf][rg] * sc);
          }
        }
    } else {
      int h = ch - 12;
      size_t base = ((size_t)b * 6 + h) * 4096;
#pragma unroll
      for (int jf = 0; jf < 2; ++jf)
#pragma unroll
        for (int tf = 0; tf < 2; ++tf) {
          int tok = rowbase + tf * 16 + lr;
#pragma unroll
          for (int rg = 0; rg < 4; ++rg) {
            int d = jf * 16 + r4 + rg;
            vb[base + (size_t)d * 128 + tok] = f2bf(acc[jf][tf][rg]);
          }
        }
    }
    if (ch < 17) {
#pragma unroll
      for (int i = 0; i < 3; ++i)
        *(short8*)(wtb + ((ch + 1) & 1) * 12288 + wdoff[i]) = wreg[i];
      __syncthreads();
    }
  }
}

// ---------------- fused attention per (window, head), barrier-free ----------------
__global__ __launch_bounds__(256, 5) void attn_kernel(const short* __restrict__ qb,
                                                      const short* __restrict__ kb,
                                                      const short* __restrict__ vb,
                                                      const float* __restrict__ bmF,
                                                      char* __restrict__ outc) {
  __shared__ short p_lds[16384];  // [128][128] bf16, swizzle byte ^= (row&15)<<4
  char* pbuf = (char*)p_lds;
  const int bh = blockIdx.x, b = bh / 6, h = bh - b * 6;
  const short* qt = qb + (size_t)bh * 4096;
  const short* kt = kb + (size_t)bh * 4096;
  const short* vt = vb + (size_t)bh * 4096;
  const float4* bm4 = (const float4*)(bmF + ((size_t)h * 64 + (b & 63)) * 16384);
  short* outSlot = (short*)(outc + (size_t)b * 98304 + 49152);
  const int tid = threadIdx.x, wave = tid >> 6, lane = tid & 63;
  const int lr = lane & 15, g = lane >> 4, lkb = g * 8, r4 = g * 4;
  const int rowbase = wave * 32;

  float inv[2][4];
#pragma unroll
  for (int rf = 0; rf < 2; ++rf) {
    short8 a0 = *(const short8*)&qt[(rowbase + rf * 16 + lr) * 32 + lkb];
    f32x4 s[8];
    __builtin_amdgcn_s_setprio(1);
#pragma unroll
    for (int cf = 0; cf < 8; ++cf) {
      short8 bb = *(const short8*)&kt[(cf * 16 + lr) * 32 + lkb];
      f32x4 z = {0.f, 0.f, 0.f, 0.f};
      s[cf] = mfma16(a0, bb, z);
    }
    __builtin_amdgcn_s_setprio(0);
#pragma unroll
    for (int rg = 0; rg < 4; ++rg) {
      int L = rf * 8 + rg * 2;
      float4 bb0 = bm4[L * 256 + tid];
      float4 bb1 = bm4[(L + 1) * 256 + tid];
      float p0 = exp2f(s[0][rg] + bb0.x);
      float p1 = exp2f(s[1][rg] + bb0.y);
      float p2 = exp2f(s[2][rg] + bb0.z);
      float p3 = exp2f(s[3][rg] + bb0.w);
      float p4 = exp2f(s[4][rg] + bb1.x);
      float p5 = exp2f(s[5][rg] + bb1.y);
      float p6 = exp2f(s[6][rg] + bb1.z);
      float p7 = exp2f(s[7][rg] + bb1.w);
      float sum = ((p0 + p1) + (p2 + p3)) + ((p4 + p5) + (p6 + p7));
#pragma unroll
      for (int o = 1; o < 16; o <<= 1) sum += __shfl_xor(sum, o);
      inv[rf][rg] = 1.0f / sum;
      int row = rowbase + rf * 16 + r4 + rg;
      int base = (row << 8) + (lr << 1);
      int swz = (row & 15) << 4;
      *(short*)(pbuf + ((base + 0 * 32) ^ swz)) = f2bf(p0);
      *(short*)(pbuf + ((base + 1 * 32) ^ swz)) = f2bf(p1);
      *(short*)(pbuf + ((base + 2 * 32) ^ swz)) = f2bf(p2);
      *(short*)(pbuf + ((base + 3 * 32) ^ swz)) = f2bf(p3);
      *(short*)(pbuf + ((base + 4 * 32) ^ swz)) = f2bf(p4);
      *(short*)(pbuf + ((base + 5 * 32) ^ swz)) = f2bf(p5);
      *(short*)(pbuf + ((base + 6 * 32) ^ swz)) = f2bf(p6);
      *(short*)(pbuf + ((base + 7 * 32) ^ swz)) = f2bf(p7);
    }
  }
  // PV: no barrier — each wave reads only its own 32 rows.
  const int rsw = lr << 4;
  f32x4 o[2][2];
  o[0][0] = o[0][1] = o[1][0] = o[1][1] = f32x4{0.f, 0.f, 0.f, 0.f};
#pragma unroll
  for (int ks = 0; ks < 4; ++ks) {
    int ra = ((rowbase + lr) << 8) + (ks << 6) + (g << 4);
    short8 pa0 = *(const short8*)(pbuf + ((ra) ^ rsw));
    short8 pa1 = *(const short8*)(pbuf + ((ra + (16 << 8)) ^ rsw));
    short8 b0 = *(const short8*)&vt[lr * 128 + ks * 32 + lkb];
    short8 b1 = *(const short8*)&vt[(16 + lr) * 128 + ks * 32 + lkb];
    __builtin_amdgcn_s_setprio(1);
    o[0][0] = mfma16(pa0, b0, o[0][0]);
    o[0][1] = mfma16(pa0, b1, o[0][1]);
    o[1][0] = mfma16(pa1, b0, o[1][0]);
    o[1][1] = mfma16(pa1, b1, o[1][1]);
    __builtin_amdgcn_s_setprio(0);
  }
#pragma unroll
  for (int rf = 0; rf < 2; ++rf)
#pragma unroll
    for (int cf = 0; cf < 2; ++cf)
#pragma unroll
      for (int rg = 0; rg < 4; ++rg) {
        int tok = rowbase + rf * 16 + r4 + rg;
        int d = cf * 16 + lr;
        outSlot[tok * 192 + h * 32 + d] = f2bf(o[rf][cf][rg] * inv[rf][rg]);
      }
}

// ---------------- proj: ain[128][192] (bf16 in own d_out slot) @ proj_w^T + b ----------------
__global__ __launch_bounds__(256, 2) void proj_kernel(const short* __restrict__ pwbf,
                                                      const float* __restrict__ pb,
                                                      float* __restrict__ out) {
  __shared__ short at[24576];
  __shared__ short wt[2][6144];
  const int b = blockIdx.x, tid = threadIdx.x;
  const int wave = tid >> 6, lane = tid & 63;
  const int lr = lane & 15, g = lane >> 4;
  const int g16 = g * 16, r4 = g * 4;
  const int rowbase = wave * 32;
  const int xorkey = (lr & 7) << 4;
  char* atb = (char*)at;
  char* wtb = (char*)wt;

  int wsoff[3], wdoff[3];
#pragma unroll
  for (int i = 0; i < 3; ++i) {
    int idx8 = i * 256 + tid;
    int r = idx8 / 24, c = idx8 - r * 24;
    wsoff[i] = idx8 * 8;
    wdoff[i] = r * 384 + ((c * 16) ^ ((r & 7) << 4));
  }
  short8 wreg[3];
#pragma unroll
  for (int i = 0; i < 3; ++i) wreg[i] = *(const short8*)(pwbf + wsoff[i]);

  // stage this block's bf16 attn-out (second half of its own d_out slot)
  const short8* ar = (const short8*)((const char*)out + (size_t)b * 98304 + 49152);
#pragma unroll
  for (int i = 0; i < 12; ++i) {
    int idx8 = i * 256 + tid;
    int r = idx8 / 24, c = idx8 - r * 24;
    short8 v = ar[idx8];
    *(short8*)(atb + r * 384 + ((c * 16) ^ ((r & 7) << 4))) = v;
  }
#pragma unroll
  for (int i = 0; i < 3; ++i) *(short8*)(wtb + wdoff[i]) = wreg[i];
  __syncthreads();

  const int rA0 = (rowbase + lr) * 384, rA1 = rA0 + 16 * 384;
  const int wB0 = lr * 384, wB1 = wB0 + 16 * 384;

  for (int ch = 0; ch < 6; ++ch) {
    if (ch < 5) {
#pragma unroll
      for (int i = 0; i < 3; ++i)
        wreg[i] = *(const short8*)(pwbf + (ch + 1) * 6144 + wsoff[i]);
    }
    const char* wbuf = wtb + (ch & 1) * 12288;
    f32x4 acc[2][2];
    acc[0][0] = acc[0][1] = acc[1][0] = acc[1][1] = f32x4{0.f, 0.f, 0.f, 0.f};
#pragma unroll
    for (int ks = 0; ks < 6; ++ks) {
      int cx = (ks * 64 + g16) ^ xorkey;
      short8 xa0 = *(const short8*)(atb + rA0 + cx);
      short8 xa1 = *(const short8*)(atb + rA1 + cx);
      short8 wf0 = *(const short8*)(wbuf + wB0 + cx);
      short8 wf1 = *(const short8*)(wbuf + wB1 + cx);
      acc[0][0] = mfma16(xa0, wf0, acc[0][0]);
      acc[0][1] = mfma16(xa0, wf1, acc[0][1]);
      acc[1][0] = mfma16(xa1, wf0, acc[1][0]);
      acc[1][1] = mfma16(xa1, wf1, acc[1][1]);
    }
#pragma unroll
    for (int cf = 0; cf < 2; ++cf) {
      int j = ch * 32 + cf * 16 + lr;
      float bj = pb[j];
#pragma unroll
      for (int rf = 0; rf < 2; ++rf)
#pragma unroll
        for (int rg = 0; rg < 4; ++rg) {
          int tok = rowbase + rf * 16 + r4 + rg;
          out[((size_t)b * 128 + tok) * 192 + j] = acc[rf][cf][rg] + bj;
        }
    }
    if (ch < 5) {
#pragma unroll
      for (int i = 0; i < 3; ++i)
        *(short8*)(wtb + ((ch + 1) & 1) * 12288 + wdoff[i]) = wreg[i];
      __syncthreads();
    }
  }
}

extern "C" void kernel_launch(void* const* d_in, const int* in_sizes, int n_in,
                              void* d_out, int out_size, void* d_ws, size_t ws_size,
                              hipStream_t stream) {
  const float* x      = (const float*)d_in[0];
  const float* mask   = (const float*)d_in[1];
  const float* qkv_w  = (const float*)d_in[2];
  const float* proj_w = (const float*)d_in[3];
  const float* proj_b = (const float*)d_in[4];
  const float* table  = (const float*)d_in[5];
  const int*   rel    = (const int*)d_in[6];
  char* ws = (char*)d_ws;
  size_t o = 0;
  float* bmF  = (float*)(ws + o); o += 25165824;   // 384 * 16384 * 4
  short* wbf  = (short*)(ws + o); o += 221184;
  short* pwbf = (short*)(ws + o); o += 73728;
  short* qbp  = (short*)(ws + o); o += 50331648;
  short* kbp  = (short*)(ws + o); o += 50331648;
  short* vbp  = (short*)(ws + o); o += 50331648;
  float* out = (float*)d_out;

  prep_w<<<144, 256, 0, stream>>>(qkv_w, proj_w, wbf, pwbf);
  prep_bm<<<384, 256, 0, stream>>>(rel, table, mask, bmF);
  qkv_kernel<<<1024, 256, 0, stream>>>(x, wbf, qbp, kbp, vbp);
  attn_kernel<<<6144, 256, 0, stream>>>(qbp, kbp, vbp, bmF, (char*)d_out);
  proj_kernel<<<1024, 256, 0, stream>>>(pwbf, proj_b, out);
}